// Round 5
// baseline (766.945 us; speedup 1.0000x reference)
//
#include <hip/hip_runtime.h>
#include <hip/hip_bf16.h>

#define N_TOK 343
#define C_DIM 96
#define H_HEADS 24
#define HD 4
#define B_WIN 32
#define SCALE_Q 0.5f
#define EPS_IN 1e-5f
#define A_ELEMS (B_WIN * H_HEADS * N_TOK * HD)   // 1,053,696 floats per [B,H,N,HD] array

// ws slot layout (each A_ELEMS floats):
//   0=q1  1=k1  2=q2  3=k2  4=v1 (reused as AO after fuse)  5=v2  6=vf
// total ws = 7 * A_ELEMS * 4 B = 29.5 MB

// ---------------- kernel 1: QKV projection for x1 and x2 ----------------
__global__ __launch_bounds__(256) void qkv_kernel(const float* __restrict__ x1,
                                                  const float* __restrict__ x2,
                                                  const float* __restrict__ w,
                                                  const float* __restrict__ bqkv,
                                                  float* __restrict__ ws) {
    __shared__ float xs[64 * C_DIM];
    const int row0 = blockIdx.x * 64;
    const int src  = blockIdx.y;
    const int b    = blockIdx.z;
    const int rows = min(64, N_TOK - row0);
    const float* x = (src == 0 ? x1 : x2) + ((size_t)b * N_TOK + row0) * C_DIM;
    for (int e = threadIdx.x; e < rows * C_DIM; e += blockDim.x) xs[e] = x[e];
    __syncthreads();
    for (int e = threadIdx.x; e < rows * 288; e += blockDim.x) {
        int r = e / 288, oc = e - r * 288;
        float acc = bqkv[oc];
        const float* wr = w + (size_t)oc * C_DIM;
        const float* xr = xs + r * C_DIM;
        #pragma unroll 8
        for (int k = 0; k < C_DIM; ++k) acc += xr[k] * wr[k];
        int s = oc / 96;
        int hc = oc - s * 96;          // h*4 + d
        if (s == 0) acc *= SCALE_Q;    // fold attention scale into q
        int slot;
        if (s == 0)      slot = src ? 2 : 0;   // q
        else if (s == 1) slot = src ? 3 : 1;   // k
        else             slot = src ? 5 : 4;   // v
        int h = hc >> 2, d = hc & 3;
        ws[(size_t)slot * A_ELEMS +
           (((size_t)b * H_HEADS + h) * N_TOK + (row0 + r)) * HD + d] = acc;
    }
}

// ---------------- kernel 2: fuse (1x1 conv 48->24 + InstanceNorm + relu + sigmoid) ----------------
__global__ __launch_bounds__(256) void fuse_kernel(const float* __restrict__ v1,
                                                   const float* __restrict__ v2,
                                                   const float* __restrict__ fw,
                                                   const float* __restrict__ fb,
                                                   float* __restrict__ vf) {
    const int o = blockIdx.x, b = blockIdx.y;
    __shared__ float ts[N_TOK * HD];
    __shared__ float red[32];
    __shared__ float fwl[48];
    if (threadIdx.x < 48) fwl[threadIdx.x] = fw[o * 48 + threadIdx.x];
    __syncthreads();
    const float bo = fb[o];
    const float* p1 = v1 + (size_t)b * H_HEADS * N_TOK * HD;
    const float* p2 = v2 + (size_t)b * H_HEADS * N_TOK * HD;
    float lsum = 0.f, lsq = 0.f;
    for (int e = threadIdx.x; e < N_TOK * HD; e += blockDim.x) {
        float acc = bo;
        #pragma unroll
        for (int c = 0; c < H_HEADS; ++c) {
            acc += fwl[c]      * p1[(size_t)c * N_TOK * HD + e];
            acc += fwl[24 + c] * p2[(size_t)c * N_TOK * HD + e];
        }
        ts[e] = acc;
        lsum += acc; lsq += acc * acc;
    }
    for (int off = 32; off; off >>= 1) {
        lsum += __shfl_xor(lsum, off);
        lsq  += __shfl_xor(lsq, off);
    }
    int wid = threadIdx.x >> 6, lane = threadIdx.x & 63;
    if (lane == 0) { red[wid] = lsum; red[8 + wid] = lsq; }
    __syncthreads();
    if (threadIdx.x == 0) {
        float s = red[0] + red[1] + red[2] + red[3];
        float q = red[8] + red[9] + red[10] + red[11];
        float mean = s / (float)(N_TOK * HD);
        float var  = q / (float)(N_TOK * HD) - mean * mean;
        red[16] = mean;
        red[17] = rsqrtf(var + EPS_IN);
    }
    __syncthreads();
    const float mean = red[16], inv = red[17];
    float* out = vf + ((size_t)b * H_HEADS + o) * N_TOK * HD;
    for (int e = threadIdx.x; e < N_TOK * HD; e += blockDim.x) {
        float x = (ts[e] - mean) * inv;
        x = fmaxf(x, 0.f);
        out[e] = 1.f / (1.f + __expf(-x));
    }
}

// ---------------- kernel 3: fused attention per (b,h), bias gathered on the fly ----------------
__global__ __launch_bounds__(256) void attn_kernel(const float* __restrict__ ws,
                                                   const float* __restrict__ rpb,
                                                   const int* __restrict__ rel,
                                                   const float* __restrict__ vf,
                                                   float* __restrict__ ao) {
    const int h = blockIdx.x, b = blockIdx.y;
    __shared__ float q1s[N_TOK * HD], q2s[N_TOK * HD];
    __shared__ float k1s[HD][N_TOK], k2s[HD][N_TOK], vs[HD][N_TOK];
    const size_t off = ((size_t)b * H_HEADS + h) * N_TOK * HD;
    const float* Q1 = ws + 0 * (size_t)A_ELEMS + off;
    const float* K1 = ws + 1 * (size_t)A_ELEMS + off;
    const float* Q2 = ws + 2 * (size_t)A_ELEMS + off;
    const float* K2 = ws + 3 * (size_t)A_ELEMS + off;
    const float* V  = vf + off;
    for (int e = threadIdx.x; e < N_TOK * HD; e += blockDim.x) {
        int n = e >> 2, d = e & 3;
        q1s[e] = Q1[e]; q2s[e] = Q2[e];
        k1s[d][n] = K1[e]; k2s[d][n] = K2[e]; vs[d][n] = V[e];
    }
    __syncthreads();
    const int wid = threadIdx.x >> 6, lane = threadIdx.x & 63;
    for (int i = wid; i < N_TOK; i += 4) {
        float q1a[4], q2a[4];
        #pragma unroll
        for (int d = 0; d < 4; ++d) { q1a[d] = q1s[i * 4 + d]; q2a[d] = q2s[i * 4 + d]; }
        const int* relRow = rel + (size_t)i * N_TOK;
        float sreg[6];
        float m = -1e30f;
        #pragma unroll
        for (int it = 0; it < 6; ++it) {
            int j = lane + it * 64;
            float s = -1e30f;
            if (j < N_TOK) {
                s = rpb[relRow[j] * H_HEADS + h];   // on-the-fly bias gather
                #pragma unroll
                for (int d = 0; d < 4; ++d)
                    s += q1a[d] * k1s[d][j] + q2a[d] * k2s[d][j];
            }
            sreg[it] = s;
            m = fmaxf(m, s);
        }
        for (int o = 32; o; o >>= 1) m = fmaxf(m, __shfl_xor(m, o));
        float sum = 0.f, a0 = 0.f, a1 = 0.f, a2 = 0.f, a3 = 0.f;
        #pragma unroll
        for (int it = 0; it < 6; ++it) {
            int j = lane + it * 64;
            if (j < N_TOK) {
                float p = __expf(sreg[it] - m);
                sum += p;
                a0 += p * vs[0][j]; a1 += p * vs[1][j];
                a2 += p * vs[2][j]; a3 += p * vs[3][j];
            }
        }
        for (int o = 32; o; o >>= 1) {
            sum += __shfl_xor(sum, o);
            a0 += __shfl_xor(a0, o); a1 += __shfl_xor(a1, o);
            a2 += __shfl_xor(a2, o); a3 += __shfl_xor(a3, o);
        }
        if (lane == 0) {
            float inv = 1.f / sum;
            float* op = ao + ((size_t)b * N_TOK + i) * C_DIM + h * HD;
            op[0] = a0 * inv; op[1] = a1 * inv; op[2] = a2 * inv; op[3] = a3 * inv;
        }
    }
}

// ---------------- kernel 4: output projection -> FLOAT32 (reference output dtype) ----------------
__global__ __launch_bounds__(256) void proj_kernel(const float* __restrict__ ao,
                                                   const float* __restrict__ pw,
                                                   const float* __restrict__ pb,
                                                   float* __restrict__ out) {
    __shared__ float xs[64 * C_DIM];
    __shared__ float pwl[C_DIM * 97];   // padded stride 97 -> no bank conflicts
    const int b = blockIdx.y, row0 = blockIdx.x * 64;
    const int rows = min(64, N_TOK - row0);
    for (int e = threadIdx.x; e < rows * C_DIM; e += blockDim.x)
        xs[e] = ao[((size_t)b * N_TOK + row0) * C_DIM + e];
    for (int e = threadIdx.x; e < C_DIM * C_DIM; e += blockDim.x) {
        int c = e / C_DIM, k = e - c * C_DIM;
        pwl[c * 97 + k] = pw[e];
    }
    __syncthreads();
    for (int e = threadIdx.x; e < rows * C_DIM; e += blockDim.x) {
        int r = e / C_DIM, c = e - r * C_DIM;
        float acc = pb[c];
        const float* xr = xs + r * C_DIM;
        const float* wr = pwl + c * 97;
        #pragma unroll 8
        for (int k = 0; k < C_DIM; ++k) acc += xr[k] * wr[k];
        out[((size_t)b * N_TOK + row0) * C_DIM + e] = acc;
    }
}

// size-based input dispatch: all element counts are unique except x1/x2,
// which keep their relative order under any stable permutation.
static const void* find_by_size(void* const* d_in, const int* in_sizes, int n_in,
                                int want, int occurrence) {
    int seen = 0;
    for (int i = 0; i < n_in; ++i) {
        if (in_sizes[i] == want) {
            if (seen == occurrence) return d_in[i];
            ++seen;
        }
    }
    return nullptr;
}

extern "C" void kernel_launch(void* const* d_in, const int* in_sizes, int n_in,
                              void* d_out, int out_size, void* d_ws, size_t ws_size,
                              hipStream_t stream) {
    const float* x1     = (const float*)find_by_size(d_in, in_sizes, n_in, 1053696, 0);
    const float* x2     = (const float*)find_by_size(d_in, in_sizes, n_in, 1053696, 1);
    const float* qkv_w  = (const float*)find_by_size(d_in, in_sizes, n_in, 27648, 0);
    const float* qkv_b  = (const float*)find_by_size(d_in, in_sizes, n_in, 288, 0);
    const float* proj_w = (const float*)find_by_size(d_in, in_sizes, n_in, 9216, 0);
    const float* proj_b = (const float*)find_by_size(d_in, in_sizes, n_in, 96, 0);
    const float* rpb    = (const float*)find_by_size(d_in, in_sizes, n_in, 52728, 0);
    const float* fuse_w = (const float*)find_by_size(d_in, in_sizes, n_in, 1152, 0);
    const float* fuse_b = (const float*)find_by_size(d_in, in_sizes, n_in, 24, 0);
    const int*   rel    = (const int*)  find_by_size(d_in, in_sizes, n_in, 117649, 0);

    // fallback to declared dict order if the size signature doesn't match
    if (!x1 || !x2 || !qkv_w || !qkv_b || !proj_w || !proj_b || !rpb || !fuse_w ||
        !fuse_b || !rel) {
        x1     = (const float*)d_in[0];
        x2     = (const float*)d_in[1];
        qkv_w  = (const float*)d_in[2];
        qkv_b  = (const float*)d_in[3];
        proj_w = (const float*)d_in[4];
        proj_b = (const float*)d_in[5];
        rpb    = (const float*)d_in[6];
        fuse_w = (const float*)d_in[7];
        fuse_b = (const float*)d_in[8];
        rel    = (const int*)d_in[9];
    }

    float* ws = (float*)d_ws;
    float* V1 = ws + 4 * (size_t)A_ELEMS;   // v1; reused as AO after fuse completes
    float* V2 = ws + 5 * (size_t)A_ELEMS;
    float* VF = ws + 6 * (size_t)A_ELEMS;
    float* AO = V1;                          // alias: v1 dead after fuse_kernel
    float* out = (float*)d_out;

    qkv_kernel<<<dim3(6, 2, B_WIN), 256, 0, stream>>>(x1, x2, qkv_w, qkv_b, ws);
    fuse_kernel<<<dim3(H_HEADS, B_WIN), 256, 0, stream>>>(V1, V2, fuse_w, fuse_b, VF);
    attn_kernel<<<dim3(H_HEADS, B_WIN), 256, 0, stream>>>(ws, rpb, rel, VF, AO);
    proj_kernel<<<dim3(6, B_WIN), 256, 0, stream>>>(AO, proj_w, proj_b, out);
}

// Round 6
// 397.753 us; speedup vs baseline: 1.9282x; 1.9282x over previous
//
#include <hip/hip_runtime.h>
#include <hip/hip_bf16.h>

#define N_TOK 343
#define N_PAD 344
#define C_DIM 96
#define H_HEADS 24
#define HD 4
#define B_WIN 32
#define SCALE_Q 0.5f
#define EPS_IN 1e-5f
// padded per-array elems: [b][h][d][n_pad]
#define CH_STR (HD * N_PAD)                    // 1376 floats per (b,h)
#define AP ((size_t)B_WIN * H_HEADS * CH_STR)  // 1,056,768 floats
// ws slots: 0=q1 1=k1 2=q2 3=k2 4=v1(->AO) 5=v2 6=vf ; total 29.6 MB

// ---------------- kernel 1: QKV projection, LDS-tiled GEMM ----------------
// grid (11 row-tiles, 3 s, 32 b), 192 threads; out layout [b][h][d][n_pad]
__global__ __launch_bounds__(192) void qkv_kernel(const float* __restrict__ x1,
                                                  const float* __restrict__ x2,
                                                  const float* __restrict__ w,
                                                  const float* __restrict__ bqkv,
                                                  float* __restrict__ ws) {
    __shared__ float wt[96 * 100];     // wt[k][j] padded 100 (float4-aligned)
    __shared__ float xs[2][32 * 97];   // xs[src][r][k] padded 97
    const int s = blockIdx.y, b = blockIdx.z, r0 = blockIdx.x * 32;
    const int rows = min(32, N_TOK - r0);
    const int tid = threadIdx.x;
    for (int e = tid; e < 96 * 96; e += 192) {
        int j = e / 96, k = e - j * 96;
        wt[k * 100 + j] = w[s * 96 * 96 + e];
    }
    const float* x1p = x1 + ((size_t)b * N_TOK + r0) * C_DIM;
    const float* x2p = x2 + ((size_t)b * N_TOK + r0) * C_DIM;
    for (int e = tid; e < rows * 96; e += 192) {
        int r = e / 96, k = e - r * 96;
        xs[0][r * 97 + k] = x1p[e];
        xs[1][r * 97 + k] = x2p[e];
    }
    __syncthreads();
    const int rg = tid & 7, og = tid >> 3;   // og 0..23, rg 0..7
    const int oc0 = og * 4, rr = rg * 4;
    float acc[2][4][4];
    #pragma unroll
    for (int i = 0; i < 4; ++i) {
        float bv = bqkv[s * 96 + oc0 + i];
        #pragma unroll
        for (int src = 0; src < 2; ++src)
            #pragma unroll
            for (int j = 0; j < 4; ++j) acc[src][i][j] = bv;
    }
    for (int k = 0; k < 96; ++k) {
        float4 w4 = *(const float4*)&wt[k * 100 + oc0];
        float wv[4] = {w4.x, w4.y, w4.z, w4.w};
        float xv0[4], xv1[4];
        #pragma unroll
        for (int j = 0; j < 4; ++j) {
            xv0[j] = xs[0][(rr + j) * 97 + k];
            xv1[j] = xs[1][(rr + j) * 97 + k];
        }
        #pragma unroll
        for (int i = 0; i < 4; ++i)
            #pragma unroll
            for (int j = 0; j < 4; ++j) {
                acc[0][i][j] += xv0[j] * wv[i];
                acc[1][i][j] += xv1[j] * wv[i];
            }
    }
    const float scl = (s == 0) ? SCALE_Q : 1.0f;
    #pragma unroll
    for (int i = 0; i < 4; ++i) {
        int oc = oc0 + i, h = oc >> 2, d = oc & 3;
        size_t base = (((size_t)b * H_HEADS + h) * HD + d) * N_PAD + r0 + rr;
        #pragma unroll
        for (int src = 0; src < 2; ++src) {
            int slot = (s == 0) ? (src ? 2 : 0) : (s == 1) ? (src ? 3 : 1) : (src ? 5 : 4);
            float* dst = ws + (size_t)slot * AP + base;
            if (r0 + rr + 3 < N_TOK) {
                *(float4*)dst = make_float4(acc[src][i][0] * scl, acc[src][i][1] * scl,
                                            acc[src][i][2] * scl, acc[src][i][3] * scl);
            } else {
                #pragma unroll
                for (int j = 0; j < 4; ++j)
                    if (r0 + rr + j < N_TOK) dst[j] = acc[src][i][j] * scl;
            }
        }
    }
}

// ---------------- kernel 2: fuse (1x1 conv 48->24 + InstanceNorm + relu + sigmoid) ----------------
__global__ __launch_bounds__(256) void fuse_kernel(const float* __restrict__ v1,
                                                   const float* __restrict__ v2,
                                                   const float* __restrict__ fw,
                                                   const float* __restrict__ fb,
                                                   float* __restrict__ vf) {
    const int o = blockIdx.x, b = blockIdx.y;
    __shared__ float ts[N_TOK * HD];
    __shared__ float red[32];
    __shared__ float fwl[48];
    if (threadIdx.x < 48) fwl[threadIdx.x] = fw[o * 48 + threadIdx.x];
    __syncthreads();
    const float bo = fb[o];
    const float* p1 = v1 + (size_t)b * H_HEADS * CH_STR;
    const float* p2 = v2 + (size_t)b * H_HEADS * CH_STR;
    float lsum = 0.f, lsq = 0.f;
    for (int e = threadIdx.x; e < N_TOK * HD; e += blockDim.x) {
        int d = e / N_TOK, n = e - d * N_TOK;
        int gi = d * N_PAD + n;
        float acc = bo;
        #pragma unroll
        for (int c = 0; c < H_HEADS; ++c) {
            acc += fwl[c]      * p1[(size_t)c * CH_STR + gi];
            acc += fwl[24 + c] * p2[(size_t)c * CH_STR + gi];
        }
        ts[e] = acc;
        lsum += acc; lsq += acc * acc;
    }
    for (int off = 32; off; off >>= 1) {
        lsum += __shfl_xor(lsum, off);
        lsq  += __shfl_xor(lsq, off);
    }
    int wid = threadIdx.x >> 6, lane = threadIdx.x & 63;
    if (lane == 0) { red[wid] = lsum; red[8 + wid] = lsq; }
    __syncthreads();
    if (threadIdx.x == 0) {
        float su = red[0] + red[1] + red[2] + red[3];
        float q  = red[8] + red[9] + red[10] + red[11];
        float mean = su / (float)(N_TOK * HD);
        float var  = q / (float)(N_TOK * HD) - mean * mean;
        red[16] = mean;
        red[17] = rsqrtf(var + EPS_IN);
    }
    __syncthreads();
    const float mean = red[16], inv = red[17];
    float* outp = vf + ((size_t)b * H_HEADS + o) * CH_STR;
    for (int e = threadIdx.x; e < N_TOK * HD; e += blockDim.x) {
        int d = e / N_TOK, n = e - d * N_TOK;
        float x = (ts[e] - mean) * inv;
        x = fmaxf(x, 0.f);
        outp[d * N_PAD + n] = 1.f / (1.f + __expf(-x));
    }
}

// ---------------- kernel 3: fused attention per (b,h) ----------------
__global__ __launch_bounds__(256) void attn_kernel(const float* __restrict__ ws,
                                                   const float* __restrict__ rpb,
                                                   const int* __restrict__ rel,
                                                   const float* __restrict__ vf,
                                                   float* __restrict__ ao) {
    const int h = blockIdx.x, b = blockIdx.y;
    __shared__ float q1s[HD * N_PAD], q2s[HD * N_PAD];
    __shared__ float k1s[HD * N_PAD], k2s[HD * N_PAD], vs[HD * N_PAD];
    const size_t off = ((size_t)b * H_HEADS + h) * CH_STR;
    const float* Q1 = ws + 0 * AP + off;
    const float* K1 = ws + 1 * AP + off;
    const float* Q2 = ws + 2 * AP + off;
    const float* K2 = ws + 3 * AP + off;
    const float* V  = vf + off;
    for (int e = threadIdx.x; e < HD * N_PAD; e += blockDim.x) {
        q1s[e] = Q1[e]; q2s[e] = Q2[e];
        k1s[e] = K1[e]; k2s[e] = K2[e]; vs[e] = V[e];
    }
    __syncthreads();
    const int wid = threadIdx.x >> 6, lane = threadIdx.x & 63;
    for (int i = wid; i < N_TOK; i += 4) {
        float q1a[4], q2a[4];
        #pragma unroll
        for (int d = 0; d < 4; ++d) {
            q1a[d] = q1s[d * N_PAD + i];
            q2a[d] = q2s[d * N_PAD + i];
        }
        const int* relRow = rel + (size_t)i * N_TOK;
        float sreg[6];
        float m = -1e30f;
        #pragma unroll
        for (int it = 0; it < 6; ++it) {
            int j = lane + it * 64;
            float s = -1e30f;
            if (j < N_TOK) {
                s = rpb[relRow[j] * H_HEADS + h];
                #pragma unroll
                for (int d = 0; d < 4; ++d)
                    s += q1a[d] * k1s[d * N_PAD + j] + q2a[d] * k2s[d * N_PAD + j];
            }
            sreg[it] = s;
            m = fmaxf(m, s);
        }
        for (int o = 32; o; o >>= 1) m = fmaxf(m, __shfl_xor(m, o));
        float sum = 0.f, a0 = 0.f, a1 = 0.f, a2 = 0.f, a3 = 0.f;
        #pragma unroll
        for (int it = 0; it < 6; ++it) {
            int j = lane + it * 64;
            if (j < N_TOK) {
                float p = __expf(sreg[it] - m);
                sum += p;
                a0 += p * vs[0 * N_PAD + j]; a1 += p * vs[1 * N_PAD + j];
                a2 += p * vs[2 * N_PAD + j]; a3 += p * vs[3 * N_PAD + j];
            }
        }
        for (int o = 32; o; o >>= 1) {
            sum += __shfl_xor(sum, o);
            a0 += __shfl_xor(a0, o); a1 += __shfl_xor(a1, o);
            a2 += __shfl_xor(a2, o); a3 += __shfl_xor(a3, o);
        }
        if (lane == 0) {
            float inv = 1.f / sum;
            float* op = ao + ((size_t)b * N_TOK + i) * C_DIM + h * HD;
            op[0] = a0 * inv; op[1] = a1 * inv; op[2] = a2 * inv; op[3] = a3 * inv;
        }
    }
}

// ---------------- kernel 4: output projection -> float32 ----------------
__global__ __launch_bounds__(256) void proj_kernel(const float* __restrict__ ao,
                                                   const float* __restrict__ pw,
                                                   const float* __restrict__ pb,
                                                   float* __restrict__ out) {
    __shared__ float xs[64 * C_DIM];
    __shared__ float pwl[C_DIM * 97];
    const int b = blockIdx.y, row0 = blockIdx.x * 64;
    const int rows = min(64, N_TOK - row0);
    for (int e = threadIdx.x; e < rows * C_DIM; e += blockDim.x)
        xs[e] = ao[((size_t)b * N_TOK + row0) * C_DIM + e];
    for (int e = threadIdx.x; e < C_DIM * C_DIM; e += blockDim.x) {
        int c = e / C_DIM, k = e - c * C_DIM;
        pwl[c * 97 + k] = pw[e];
    }
    __syncthreads();
    for (int e = threadIdx.x; e < rows * C_DIM; e += blockDim.x) {
        int r = e / C_DIM, c = e - r * C_DIM;
        float acc = pb[c];
        const float* xr = xs + r * C_DIM;
        const float* wr = pwl + c * 97;
        #pragma unroll 8
        for (int k = 0; k < C_DIM; ++k) acc += xr[k] * wr[k];
        out[((size_t)b * N_TOK + row0) * C_DIM + e] = acc;
    }
}

static const void* find_by_size(void* const* d_in, const int* in_sizes, int n_in,
                                int want, int occurrence) {
    int seen = 0;
    for (int i = 0; i < n_in; ++i) {
        if (in_sizes[i] == want) {
            if (seen == occurrence) return d_in[i];
            ++seen;
        }
    }
    return nullptr;
}

extern "C" void kernel_launch(void* const* d_in, const int* in_sizes, int n_in,
                              void* d_out, int out_size, void* d_ws, size_t ws_size,
                              hipStream_t stream) {
    const float* x1     = (const float*)find_by_size(d_in, in_sizes, n_in, 1053696, 0);
    const float* x2     = (const float*)find_by_size(d_in, in_sizes, n_in, 1053696, 1);
    const float* qkv_w  = (const float*)find_by_size(d_in, in_sizes, n_in, 27648, 0);
    const float* qkv_b  = (const float*)find_by_size(d_in, in_sizes, n_in, 288, 0);
    const float* proj_w = (const float*)find_by_size(d_in, in_sizes, n_in, 9216, 0);
    const float* proj_b = (const float*)find_by_size(d_in, in_sizes, n_in, 96, 0);
    const float* rpb    = (const float*)find_by_size(d_in, in_sizes, n_in, 52728, 0);
    const float* fuse_w = (const float*)find_by_size(d_in, in_sizes, n_in, 1152, 0);
    const float* fuse_b = (const float*)find_by_size(d_in, in_sizes, n_in, 24, 0);
    const int*   rel    = (const int*)  find_by_size(d_in, in_sizes, n_in, 117649, 0);

    if (!x1 || !x2 || !qkv_w || !qkv_b || !proj_w || !proj_b || !rpb || !fuse_w ||
        !fuse_b || !rel) {
        x1     = (const float*)d_in[0];
        x2     = (const float*)d_in[1];
        qkv_w  = (const float*)d_in[2];
        qkv_b  = (const float*)d_in[3];
        proj_w = (const float*)d_in[4];
        proj_b = (const float*)d_in[5];
        rpb    = (const float*)d_in[6];
        fuse_w = (const float*)d_in[7];
        fuse_b = (const float*)d_in[8];
        rel    = (const int*)d_in[9];
    }

    float* ws = (float*)d_ws;
    float* V1 = ws + 4 * AP;
    float* V2 = ws + 5 * AP;
    float* VF = ws + 6 * AP;
    float* AO = V1;            // alias: v1 dead after fuse_kernel (AO needs 1,053,696 < AP)
    float* out = (float*)d_out;

    qkv_kernel<<<dim3(11, 3, B_WIN), 192, 0, stream>>>(x1, x2, qkv_w, qkv_b, ws);
    fuse_kernel<<<dim3(H_HEADS, B_WIN), 256, 0, stream>>>(V1, V2, fuse_w, fuse_b, VF);
    attn_kernel<<<dim3(H_HEADS, B_WIN), 256, 0, stream>>>(ws, rpb, rel, VF, AO);
    proj_kernel<<<dim3(6, B_WIN), 256, 0, stream>>>(AO, proj_w, proj_b, out);
}